// Round 5
// baseline (927.182 us; speedup 1.0000x reference)
//
#include <hip/hip_runtime.h>

typedef __bf16 bf16_t;
typedef bf16_t bf16x8 __attribute__((ext_vector_type(8)));
typedef bf16_t bf16x4 __attribute__((ext_vector_type(4)));
typedef float  f32x4  __attribute__((ext_vector_type(4)));

typedef const __attribute__((address_space(1))) void* gptr_t;
typedef __attribute__((address_space(3))) void* sptr_t;

#define BATCH 8
#define SEQL  4096
#define DIM   1024
#define MROWS 32768

__device__ __forceinline__ float sigmoidf_(float v) {
    return 1.0f / (1.0f + __expf(-v));
}

// ---------------- transpose + cast fp32 (K,N) -> bf16 (N,K) ----------------
// PERM=1: permute output row n so GEMM3 tiles hold (ig,fg) pairs:
//   n<1024 (ig col d): dest = (d>>6)*128 + (d&63)
//   n>=1024 (fg col d): dest = (d>>6)*128 + 64 + (d&63)
template <int PERM>
__global__ void transpose_cast(const float* __restrict__ W, bf16_t* __restrict__ WT,
                               int K, int N) {
    __shared__ float s[32][33];
    int tx = threadIdx.x, ty = threadIdx.y;
    int x = blockIdx.x * 32 + tx;   // N index
    int y = blockIdx.y * 32 + ty;   // K index
    s[ty][tx] = W[(size_t)y * N + x];
    __syncthreads();
    int n = blockIdx.x * 32 + ty;
    int k = blockIdx.y * 32 + tx;
    int nd = n;
    if (PERM) {
        if (n < 1024) nd = ((n >> 6) << 7) + (n & 63);
        else          nd = (((n - 1024) >> 6) << 7) + 64 + ((n - 1024) & 63);
    }
    WT[(size_t)nd * K + k] = (bf16_t)s[tx][ty];
}

// ---------------- scan phase 1: per-chunk sums (full D per block) ----------
__global__ void scan_chunks(const float* __restrict__ x, float* __restrict__ cs) {
    int tid = threadIdx.x;
    int b = blockIdx.x >> 6, c = blockIdx.x & 63;
    const f32x4* x4 = (const f32x4*)x;
    size_t base = ((size_t)b * SEQL + (size_t)c * 64) * 256 + tid;
    f32x4 s0 = {0.f, 0.f, 0.f, 0.f}, s1 = {0.f, 0.f, 0.f, 0.f};
#pragma unroll 8
    for (int j = 0; j < 64; j += 2) {
        s0 += x4[base + (size_t)j * 256];
        s1 += x4[base + (size_t)(j + 1) * 256];
    }
    ((f32x4*)cs)[((size_t)(b << 6) + c) * 256 + tid] = s0 + s1;
}

// ---------------- scan phase 2: exclusive prefix over 64 chunks -------------
__global__ void scan_prefix(float* __restrict__ cs) {
    int t = blockIdx.x * 256 + threadIdx.x;   // 8192 threads
    int b = t >> 10, d = t & 1023;
    size_t base = (size_t)(b << 6) * 1024 + d;
    float v[64];
#pragma unroll
    for (int c = 0; c < 64; ++c) v[c] = cs[base + (size_t)c * 1024];
    float run = 0.f;
#pragma unroll
    for (int c = 0; c < 64; ++c) {
        float tv = v[c];
        cs[base + (size_t)c * 1024] = run;
        run += tv;
    }
}

// ---------------- scan phase 3 fused: avg + LayerNorm(bf16 h) + x cast ------
__global__ __launch_bounds__(256) void scan_ln(
    const float* __restrict__ x, const float* __restrict__ cs,
    const float* __restrict__ g, const float* __restrict__ bb,
    float* __restrict__ avg, bf16_t* __restrict__ hb, bf16_t* __restrict__ xb) {
    int tid = threadIdx.x;
    int wave = tid >> 6, lane = tid & 63;
    int b = blockIdx.x >> 6, c = blockIdx.x & 63;
    __shared__ float red[8];
    const f32x4* x4 = (const f32x4*)x;
    f32x4* avg4 = (f32x4*)avg;
    bf16x4* hb4 = (bf16x4*)hb;
    bf16x4* xb4 = (bf16x4*)xb;
    f32x4 run = ((const f32x4*)cs)[((size_t)(b << 6) + c) * 256 + tid];
    f32x4 gv = ((const f32x4*)g)[tid];
    f32x4 bv = ((const f32x4*)bb)[tid];
    size_t row0 = (size_t)b * SEQL + (size_t)c * 64;
    f32x4 xv = x4[row0 * 256 + tid];
    for (int j = 0; j < 64; ++j) {
        size_t ridx = (row0 + j) * 256 + tid;
        f32x4 xnext = {0.f, 0.f, 0.f, 0.f};
        if (j < 63) xnext = x4[ridx + 256];           // prefetch next row
        run += xv;
        float inv = 1.0f / (float)(c * 64 + j + 1);
        f32x4 av = run * inv;
        avg4[ridx] = av;
        bf16x4 xo = { (bf16_t)xv[0], (bf16_t)xv[1], (bf16_t)xv[2], (bf16_t)xv[3] };
        xb4[ridx] = xo;
        float s  = av[0] + av[1] + av[2] + av[3];
        float sq = av[0]*av[0] + av[1]*av[1] + av[2]*av[2] + av[3]*av[3];
#pragma unroll
        for (int off = 32; off; off >>= 1) {
            s  += __shfl_xor(s, off);
            sq += __shfl_xor(sq, off);
        }
        if (lane == 0) { red[wave] = s; red[4 + wave] = sq; }
        __syncthreads();
        s  = red[0] + red[1] + red[2] + red[3];
        sq = red[4] + red[5] + red[6] + red[7];
        float mu  = s * (1.f / DIM);
        float var = sq * (1.f / DIM) - mu * mu;
        var = var < 0.f ? 0.f : var;
        float rs = 1.0f / sqrtf(var + 1e-6f);
        f32x4 hn = (av - mu) * rs * gv + bv;
        bf16x4 ho = { (bf16_t)hn[0], (bf16_t)hn[1], (bf16_t)hn[2], (bf16_t)hn[3] };
        hb4[ridx] = ho;
        __syncthreads();   // red[] reused next iteration
        xv = xnext;
    }
}

// ---------------- MFMA bf16 GEMM, 256x128 tile, BK=32, 4 waves --------------
// Designed for TWO independent blocks per CU (LDS 72 KB x2 = 144 <= 160 KB,
// VGPR <= 256 via launch_bounds(256,2)): one block's barrier/vmcnt/epilogue
// stalls are overlapped by the other block's MFMA (m114 mechanism), and the
// per-round prologue/epilogue tails overlap across co-resident blocks.
// Triple-buffered LDS (3 x [A 256x32 + B 128x32] bf16 = 3 x 24 KB): tile t+2
// staged while computing t -> counted vmcnt(6) never drains the pipeline.
// Per K-step (BK=32): 2 phases; each = {ds_read 4-8 x b128; stage half
// (2-4 DMA); [vmcnt(6) in P1]; s_barrier; lgkmcnt(0); 16 MFMA setprio(1);
// s_barrier}.
// Swizzle (4 chunks of 16B per 32-elem row): LDS slot (row,ch) holds global
// chunk ch ^ ((row>>1)&3)  => rows 0-7 cover all 32 banks exactly once ->
// <=2-way over a wave (free). Stage side applies the same XOR on the SOURCE
// k-offset (involution), DMA dest stays linear.
// Tail staging (tiles nT..nT+1) is clamped to k0 = K-32: issue counts and LDS
// targets unchanged (pipeline bookkeeping intact), but all source addresses
// stay inside the legitimate arrays; results are never read.
// C = A @ Bt^T ; A row stride = kSplit; A source switches at k=kSplit.
// EPI 1: outb = bf16(relu(acc + bias[n]))
// EPI 2: v = acc + bias[n] + addsrc; outf = v; outb = bf16(v)
// EPI 4: fused gating; tile covers ONE 128-col gate pair group T = n0>>7:
//        wn=0 wave -> ig col T*64+dc, wn=64 wave -> fg col 1024+T*64+dc;
//        out[row,d] = sig(ig)*xsrc + sig(fg)*addsrc, exchanged via LDS.
template <int EPI>
__global__ __launch_bounds__(256, 2) void gemm_bt(
    const bf16_t* __restrict__ A0, const bf16_t* __restrict__ A1, int kSplit,
    const bf16_t* __restrict__ Bt, int N, int K,
    const float* __restrict__ bias, const float* __restrict__ addsrc,
    const float* __restrict__ xsrc,
    float* __restrict__ outf, bf16_t* __restrict__ outb) {
    __shared__ char smem[73728];           // 3 x (16K A + 8K B)
    const int tid = threadIdx.x;
    const int wave = tid >> 6, lane = tid & 63;

    // XCD-aware bijective swizzle (all our grids are %8 == 0)
    const int nwg = gridDim.x;
    const int q8 = nwg >> 3;
    const int lid = (blockIdx.x & 7) * q8 + ((int)blockIdx.x >> 3);
    const int nBlocks = N >> 7;
    const int m0 = (lid / nBlocks) << 8;   // 256 rows
    const int n0 = (lid % nBlocks) << 7;   // 128 cols
    const int wm = (wave >> 1) << 7;       // 0 / 128
    const int wn = (wave & 1) << 6;        // 0 / 64
    const int lrow16 = lane & 15;
    // swizzled k-offset (elements): chunk (lane>>4) ^ row-bits ((lane>>1)&3)
    const int ksw = (((lane >> 4) ^ ((lane >> 1) & 3)) << 3);

    f32x4 acc[8][4] = {};

    // ---- staging: A tile = 4 DMA/thread, B tile = 2 DMA/thread ----
    auto stageA = [&](int kt, int buf) {
        int k0 = kt << 5;
        if (k0 > K - 32) k0 = K - 32;      // clamp dead tail prefetch in-array
        const bf16_t* Asrc; int ak0;
        if (k0 < kSplit) { Asrc = A0; ak0 = k0; }
        else             { Asrc = A1; ak0 = k0 - kSplit; }
        char* base = smem + buf * 24576;
#pragma unroll
        for (int rd = 0; rd < 4; ++rd) {
            int ci = tid + (rd << 8);
            int row = ci >> 2, ch = ci & 3;
            int chs = ch ^ ((row >> 1) & 3);
            const bf16_t* gp = Asrc + (size_t)(m0 + row) * kSplit + ak0 + (chs << 3);
            bf16_t* sb = (bf16_t*)base + (size_t)(ci & ~63) * 8;
            __builtin_amdgcn_global_load_lds((gptr_t)gp, (sptr_t)sb, 16, 0, 0);
        }
    };
    auto stageB = [&](int kt, int buf) {
        int k0 = kt << 5;
        if (k0 > K - 32) k0 = K - 32;      // clamp dead tail prefetch in-array
        char* base = smem + buf * 24576 + 16384;
#pragma unroll
        for (int rd = 0; rd < 2; ++rd) {
            int ci = tid + (rd << 8);
            int row = ci >> 2, ch = ci & 3;
            int chs = ch ^ ((row >> 1) & 3);
            const bf16_t* gp = Bt + (size_t)(n0 + row) * K + k0 + (chs << 3);
            bf16_t* sb = (bf16_t*)base + (size_t)(ci & ~63) * 8;
            __builtin_amdgcn_global_load_lds((gptr_t)gp, (sptr_t)sb, 16, 0, 0);
        }
    };

    bf16x8 af[4], bfv[4];
    auto readA4 = [&](int buf, int half) {
        const bf16_t* As_ = (const bf16_t*)(smem + buf * 24576);
#pragma unroll
        for (int mi = 0; mi < 4; ++mi)
            af[mi] = *(const bf16x8*)&As_[(wm + (half * 4 + mi) * 16 + lrow16) * 32 + ksw];
    };
    auto readB4 = [&](int buf) {
        const bf16_t* Bs_ = (const bf16_t*)(smem + buf * 24576 + 16384);
#pragma unroll
        for (int ni = 0; ni < 4; ++ni)
            bfv[ni] = *(const bf16x8*)&Bs_[(wn + ni * 16 + lrow16) * 32 + ksw];
    };
    auto mfma16 = [&](int half) {
        __builtin_amdgcn_s_setprio(1);
#pragma unroll
        for (int mi = 0; mi < 4; ++mi)
#pragma unroll
            for (int ni = 0; ni < 4; ++ni)
                acc[half * 4 + mi][ni] = __builtin_amdgcn_mfma_f32_16x16x32_bf16(
                    af[mi], bfv[ni], acc[half * 4 + mi][ni], 0, 0, 0);
        __builtin_amdgcn_s_setprio(0);
    };

#define BAR_  __builtin_amdgcn_s_barrier()
#define SB_   __builtin_amdgcn_sched_barrier(0)
#define LG0_  asm volatile("s_waitcnt lgkmcnt(0)" ::: "memory")
#define VMW6_ asm volatile("s_waitcnt vmcnt(6)" ::: "memory")

    // prologue: tiles 0,1 (12 DMA); vmcnt(6) -> tile0's 6 landed
    stageA(0, 0); stageB(0, 0);
    stageA(1, 1); stageB(1, 1);
    VMW6_;
    BAR_;

    const int nT = K >> 5;
    int cb = 0, st = 2;                     // compute buf, stage buf
#pragma nounroll
    for (int t = 0; t < nT; ++t) {
        // P0: B + A-half0 reads | stage A(t+2)
        readB4(cb); readA4(cb, 0);
        stageA(t + 2, st);
        BAR_; LG0_; SB_; mfma16(0); BAR_;
        // P1: A-half1 reads | stage B(t+2) | vmcnt(6): tile t+1 landed
        readA4(cb, 1);
        stageB(t + 2, st);
        VMW6_;
        BAR_; LG0_; SB_; mfma16(1); BAR_;
        cb = (cb == 2) ? 0 : cb + 1;
        st = (st == 2) ? 0 : st + 1;
    }
    asm volatile("s_waitcnt vmcnt(0)" ::: "memory");   // drain tail stages

#undef BAR_
#undef SB_
#undef LG0_
#undef VMW6_

    const int erow = (lane >> 4) << 2;

    if (EPI == 4) {
        __syncthreads();                    // tail DMAs drained in all waves
        float* xch = (float*)smem;          // [256][64] fp32 exchange (64 KB)
        const int T = n0 >> 7;
        if (wn) {                           // fg waves (cols 64..127 of tile)
#pragma unroll
            for (int mi = 0; mi < 8; ++mi) {
#pragma unroll
                for (int ni = 0; ni < 4; ++ni) {
                    int dc = ni * 16 + lrow16;            // 0..63
                    float bcol = bias[1024 + T * 64 + dc];
                    int d = T * 64 + dc;
#pragma unroll
                    for (int r = 0; r < 4; ++r) {
                        int rowW = mi * 16 + erow + r;    // 0..127
                        int row = m0 + wm + rowW;
                        float v = acc[mi][ni][r] + bcol;
                        int sw = ((rowW >> 2) & 1) << 4;  // bank de-conflict
                        xch[(wm + rowW) * 64 + (dc ^ sw)] =
                            sigmoidf_(v) * addsrc[(size_t)row * 1024 + d];
                    }
                }
            }
        }
        __syncthreads();
        if (!wn) {                          // ig waves (cols 0..63 of tile)
#pragma unroll
            for (int mi = 0; mi < 8; ++mi) {
#pragma unroll
                for (int ni = 0; ni < 4; ++ni) {
                    int dc = ni * 16 + lrow16;            // 0..63
                    float bcol = bias[T * 64 + dc];
                    int d = T * 64 + dc;
#pragma unroll
                    for (int r = 0; r < 4; ++r) {
                        int rowW = mi * 16 + erow + r;
                        int row = m0 + wm + rowW;
                        float v = acc[mi][ni][r] + bcol;
                        int sw = ((rowW >> 2) & 1) << 4;
                        float tot = sigmoidf_(v) * xsrc[(size_t)row * 1024 + d]
                                  + xch[(wm + rowW) * 64 + (dc ^ sw)];
                        outf[(size_t)row * 1024 + d] = tot;
                    }
                }
            }
        }
        return;
    }

#pragma unroll
    for (int mi = 0; mi < 8; ++mi) {
#pragma unroll
        for (int ni = 0; ni < 4; ++ni) {
            int col = n0 + wn + ni * 16 + lrow16;
            float bcol = bias[col];
#pragma unroll
            for (int r = 0; r < 4; ++r) {
                int row = m0 + wm + mi * 16 + erow + r;
                size_t idx = (size_t)row * N + col;
                float v = acc[mi][ni][r];
                if (EPI == 1) {
                    v += bcol;
                    v = v > 0.f ? v : 0.f;
                    outb[idx] = (bf16_t)v;
                } else {  // EPI == 2
                    v += bcol + addsrc[idx];
                    outf[idx] = v;
                    outb[idx] = (bf16_t)v;
                }
            }
        }
    }
}

// ---------------- launch ----------------
extern "C" void kernel_launch(void* const* d_in, const int* in_sizes, int n_in,
                              void* d_out, int out_size, void* d_ws, size_t ws_size,
                              hipStream_t stream) {
    const float* inp  = (const float*)d_in[0];
    const float* w1   = (const float*)d_in[1];
    const float* b1   = (const float*)d_in[2];
    const float* w2   = (const float*)d_in[3];
    const float* b2   = (const float*)d_in[4];
    const float* ln_g = (const float*)d_in[5];
    const float* ln_b = (const float*)d_in[6];
    const float* wg   = (const float*)d_in[7];
    const float* bg   = (const float*)d_in[8];
    float* out = (float*)d_out;

    char* w = (char*)d_ws;
    float*  avg    = (float*)w;   w += (size_t)MROWS * DIM * 4;       // 128 MB
    float*  avgout = (float*)w;   w += (size_t)MROWS * DIM * 4;       // 128 MB
    bf16_t* xb     = (bf16_t*)w;  w += (size_t)MROWS * DIM * 2;       // 64 MB
    bf16_t* hb     = (bf16_t*)w;  w += (size_t)MROWS * DIM * 2;       // 64 MB
    bf16_t* interb = (bf16_t*)w;  w += (size_t)MROWS * DIM * 2;       // 64 MB
    bf16_t* w1t    = (bf16_t*)w;  w += (size_t)DIM * DIM * 2;         // 2 MB
    bf16_t* w2t    = (bf16_t*)w;  w += (size_t)DIM * DIM * 2;         // 2 MB
    bf16_t* wgt    = (bf16_t*)w;  w += (size_t)2 * DIM * 2 * DIM * 2; // 8 MB
    float*  csum   = (float*)w;   w += (size_t)BATCH * 64 * DIM * 4;  // 2 MB
    bf16_t* aob    = hb;            // alias: h dead after GEMM1

    // weight transposes (fp32 KxN -> bf16 NxK); wg gets the ig/fg interleave
    transpose_cast<0><<<dim3(32, 32), dim3(32, 32), 0, stream>>>(w1, w1t, DIM, DIM);
    transpose_cast<0><<<dim3(32, 32), dim3(32, 32), 0, stream>>>(w2, w2t, DIM, DIM);
    transpose_cast<1><<<dim3(64, 64), dim3(32, 32), 0, stream>>>(wg, wgt, 2 * DIM, 2 * DIM);

    // prefix-mean scan + fused LN/cast
    scan_chunks<<<BATCH * 64, 256, 0, stream>>>(inp, csum);
    scan_prefix<<<32, 256, 0, stream>>>(csum);
    scan_ln<<<BATCH * 64, 256, 0, stream>>>(inp, csum, ln_g, ln_b, avg, hb, xb);

    // GEMM1: inter = relu(h @ w1 + b1)
    gemm_bt<1><<<(MROWS / 256) * (DIM / 128), 256, 0, stream>>>(
        hb, hb, DIM, w1t, DIM, DIM, b1, nullptr, nullptr, nullptr, interb);

    // GEMM2: avg_out = inter @ w2 + b2 + avg  (fp32 + bf16 stores)
    gemm_bt<2><<<(MROWS / 256) * (DIM / 128), 256, 0, stream>>>(
        interb, interb, DIM, w2t, DIM, DIM, b2, avg, nullptr, avgout, aob);

    // GEMM3 + gating fused: out = sig(ig)*x + sig(fg)*avg_out
    gemm_bt<4><<<(MROWS / 256) * (2 * DIM / 128), 256, 0, stream>>>(
        xb, aob, DIM, wgt, 2 * DIM, 2 * DIM, bg, avgout, inp, out, nullptr);
}